// Round 9
// baseline (96.363 us; speedup 1.0000x reference)
//
#include <hip/hip_runtime.h>

#define BB 4
#define CC 32
#define HH 512
#define WW 512
#define TS 16
#define SW 36        // LDS pitch: bank rotates by 4 per row; 4 | 36 -> stage16 chunks never straddle rows
#define NSLOT 1024   // 4 panels x 256 floats = rows 0..27 full
#define ROWS_OK 26   // taps: r0 in [0,26] so r0+1 <= 27
#define COLS_OK 34   // c0 in [0,34] so c0+1 <= 35
#define DEPTH 4      // prefetch depth (4 LDS buffers)

typedef float f2v __attribute__((ext_vector_type(2), aligned(4)));
typedef const __attribute__((address_space(1))) float gfloat;
typedef __attribute__((address_space(3))) float lfloat;

template<int N> __device__ __forceinline__ void waitvm() {
    asm volatile("s_waitcnt vmcnt(%0)" :: "n"(N) : "memory");
}
#define WAITLGKM() asm volatile("s_waitcnt lgkmcnt(0)" ::: "memory")

__device__ __forceinline__ void stage16(const float* g, float* l) {
    // async global->LDS: per-lane contiguous 16B global src, linear LDS dest
    // (uniform base + lane*16B). TA fast path.
    __builtin_amdgcn_global_load_lds((gfloat*)g, (lfloat*)l, 16, 0, 0);
}

__global__ __launch_bounds__(256) void warp_bilinear_kernel(
    const float* __restrict__ src,
    const float* __restrict__ flow,
    float* __restrict__ out)
{
    const int HW = HH * WW;
    __shared__ float smem[DEPTH * NSLOT];   // 16 KB -> 8 blocks/CU (thread-capped)

    // Bijective XCD swizzle (gridDim.x == 4096, divisible by 8).
    int nper = gridDim.x >> 3;
    int bid = (blockIdx.x & 7) * nper + (blockIdx.x >> 3);

    int b  = bid >> 10;
    int ty = (bid >> 5) & 31;
    int tx = bid & 31;

    int tid  = threadIdx.x;
    int lane = tid & 63;
    int wv   = tid >> 6;        // wave wv stages panel wv (floats [wv*256, wv*256+256))
    int lx   = tid & 15;
    int ly   = tid >> 4;

    int h = ty * TS + ly;
    int w = tx * TS + lx;
    int p = h * WW + w;

    int row_base = ty * TS - 4;     // staged window origin
    int col_base = tx * TS - 4;

    const float* sb = src + (size_t)b * CC * HW;
    float*       ob = out + (size_t)b * CC * HW;

    float fy = __builtin_nontemporal_load(flow + (b * 2 + 0) * HW + p);
    float fx = __builtin_nontemporal_load(flow + (b * 2 + 1) * HW + p);

    float yy = fminf(fmaxf((float)h + fy, 0.0f), (float)(HH - 1));
    float xx = fminf(fmaxf((float)w + fx, 0.0f), (float)(WW - 1));

    // Border fold (== reference exactly): x1 = x0+1 / y1 = y0+1 always,
    // with the off-edge tap getting weight exactly 0.
    int y0 = min((int)floorf(yy), HH - 2);
    int x0 = min((int)floorf(xx), WW - 2);
    float wy = yy - (float)y0;
    float wx = xx - (float)x0;

    float w00 = (1.0f - wy) * (1.0f - wx);
    float w01 = (1.0f - wy) * wx;
    float w10 = wy * (1.0f - wx);
    float w11 = wy * wx;

    int r0 = y0 - row_base;
    int c0 = x0 - col_base;
    // Staged slot (r,c) = src[clamp(row_base+r)][clamp(col_base+c)] -> exact
    // for every in-window tap (image-edge clamps match reference semantics).
    bool in_tile = ((unsigned)r0 <= ROWS_OK) && ((unsigned)c0 <= COLS_OK);
    int rc  = min(max(r0, 0), ROWS_OK);
    int cc2 = min(max(c0, 0), COLS_OK);
    int lbase = rc * SW + cc2;       // taps: +0, +1, +SW, +SW+1

    int i0 = y0 * WW + x0;           // rare out-of-halo fallback (P ~ 6e-5/pixel)
    int i1 = i0 + WW;

    bool interior_x = (tx >= 1) && (tx <= 30);   // block-uniform

    // Interior staging source: float slot f = wv*256 + lane*4, r = f/36,
    // c = f%36 in {0,4,...,32} -> 16B chunk never leaves row r.
    int f   = (wv << 8) + (lane << 2);
    int rr  = f / SW;
    int ccs = f - rr * SW;
    int srow = min(max(row_base + rr, 0), HH - 1);
    int soff = srow * WW + col_base + ccs;

    auto stage = [&](int ch) {
        float* buf = smem + (ch & (DEPTH - 1)) * NSLOT;
        if (interior_x) {
            stage16(sb + (size_t)ch * HW + soff, buf + (wv << 8));
        } else {
            const float* s = sb + (size_t)ch * HW;
            #pragma unroll
            for (int it = 0; it < 4; ++it) {
                int s2 = (wv << 8) + (it << 6) + lane;
                int r2 = s2 / SW, c2 = s2 - r2 * SW;
                int sr = min(max(row_base + r2, 0), HH - 1);
                int sc = min(max(col_base + c2, 0), WW - 1);
                buf[s2] = s[sr * WW + sc];
            }
        }
    };

    auto compute = [&](int ch) {
        const float* lb = smem + (ch & (DEPTH - 1)) * NSLOT;
        float v = lb[lbase]      * w00 + lb[lbase + 1]      * w01
                + lb[lbase + SW] * w10 + lb[lbase + SW + 1] * w11;
        if (!in_tile) {              // execz-skipped ~99.6% of waves
            const float* s = sb + (size_t)ch * HW;
            f2v t  = *(const f2v*)(s + i0);
            f2v bt = *(const f2v*)(s + i1);
            v = t.x * w00 + t.y * w01 + bt.x * w10 + bt.y * w11;
        }
        __builtin_nontemporal_store(v, ob + (size_t)ch * HW + p);
    };

    // ---- prologue: prime all DEPTH buffers ----
    stage(0); stage(1); stage(2); stage(3);

    // ---- 4-deep pipeline: wait(stage ch) / barrier / compute / barrier /
    //      stage(ch+4). Counted wait N(ch) = (#stages newer) + (#stores newer)
    //      = min(3,31-ch) + min(3,ch); in-order VMEM retirement makes
    //      "outstanding <= N" imply stage(ch) retired. Fallback loads only add
    //      newer entries -> waits become MORE conservative, never less.
    #pragma unroll
    for (int ch = 0; ch < CC; ++ch) {
        if (interior_x) {
            int nw = min(3, 31 - ch) + min(3, ch);   // constant-folded per iter
            switch (nw) {
                case 3: waitvm<3>(); break;
                case 4: waitvm<4>(); break;
                case 5: waitvm<5>(); break;
                default: waitvm<6>(); break;
            }
        } else {
            WAITLGKM();          // edge-x: drains ds_writes of stages <= ch+3
        }
        __builtin_amdgcn_s_barrier();    // all panels of buffer(ch) staged
        compute(ch);
        __builtin_amdgcn_s_barrier();    // all reads of buffer(ch) done
        if (ch + DEPTH < CC) stage(ch + DEPTH);
    }
}

extern "C" void kernel_launch(void* const* d_in, const int* in_sizes, int n_in,
                              void* d_out, int out_size, void* d_ws, size_t ws_size,
                              hipStream_t stream) {
    const float* src  = (const float*)d_in[0];
    const float* flow = (const float*)d_in[1];
    float* out = (float*)d_out;

    const int nblocks = BB * (HH / TS) * (WW / TS);   // 4096, divisible by 8
    warp_bilinear_kernel<<<nblocks, 256, 0, stream>>>(src, flow, out);
}

// Round 10
// 80.826 us; speedup vs baseline: 1.1922x; 1.1922x over previous
//
#include <hip/hip_runtime.h>

#define BB 4
#define CC 32
#define HH 512
#define WW 512

// 8-byte vector load with only 4-byte alignment guarantee (x0 may be odd).
typedef float f2v __attribute__((ext_vector_type(2), aligned(4)));

__global__ __launch_bounds__(256, 4) void warp_bilinear_kernel(
    const float* __restrict__ src,
    const float* __restrict__ flow,
    float* __restrict__ out)
{
    const int HW = HH * WW;

    // Bijective XCD swizzle (gridDim.x == 4096, divisible by 8).
    int nper = gridDim.x >> 3;
    int bid = (blockIdx.x & 7) * nper + (blockIdx.x >> 3);

    int idx = bid * blockDim.x + threadIdx.x;   // pixel index in [0, B*H*W)

    int b = idx >> 18;            // HW = 2^18
    int p = idx & (HW - 1);
    int h = p >> 9;               // WW = 2^9
    int w = p & (WW - 1);

    // flow channel 0 = y offset, channel 1 = x offset (streamed once -> nt)
    float fy = __builtin_nontemporal_load(flow + (b * 2 + 0) * HW + p);
    float fx = __builtin_nontemporal_load(flow + (b * 2 + 1) * HW + p);

    float y = fminf(fmaxf((float)h + fy, 0.0f), (float)(HH - 1));
    float x = fminf(fmaxf((float)w + fx, 0.0f), (float)(WW - 1));

    // Border fold: x0 = min(floor(x), W-2) with wx = x - x0 reproduces the
    // reference (floor + clamped neighbor) exactly; at x == W-1 the far tap
    // weight is exactly 1 and the pair load covers x0 = W-2, x1 = W-1.
    // Guarantees x1 == x0+1 / y1 == y0+1 -> each row-tap is ONE float2 load.
    int y0 = min((int)floorf(y), HH - 2);
    int x0 = min((int)floorf(x), WW - 2);
    float wy = y - (float)y0;
    float wx = x - (float)x0;

    float w00 = (1.0f - wy) * (1.0f - wx);
    float w01 = (1.0f - wy) * wx;
    float w10 = wy * (1.0f - wx);
    float w11 = wy * wx;

    int i0 = y0 * WW + x0;        // top pair    (x0, x0+1)
    int i1 = i0 + WW;             // bottom pair

    const float* sb = src + (size_t)b * CC * HW;
    float*       ob = out + (size_t)b * CC * HW;

    // 16 channels per batch: 32 dwordx2 gathers in flight per wait point
    // (vs 16 in the 8-batch variant) -> half the latency-exposed waits.
    #pragma unroll
    for (int c0 = 0; c0 < CC; c0 += 16) {
        f2v t[16], bt[16];
        #pragma unroll
        for (int k = 0; k < 16; ++k) {
            const float* s = sb + (c0 + k) * HW;
            t[k]  = *(const f2v*)(s + i0);
            bt[k] = *(const f2v*)(s + i1);
        }
        #pragma unroll
        for (int k = 0; k < 16; ++k) {
            float v = t[k].x * w00 + t[k].y * w01
                    + bt[k].x * w10 + bt[k].y * w11;
            __builtin_nontemporal_store(v, ob + (c0 + k) * HW + p);
        }
    }
}

extern "C" void kernel_launch(void* const* d_in, const int* in_sizes, int n_in,
                              void* d_out, int out_size, void* d_ws, size_t ws_size,
                              hipStream_t stream) {
    const float* src  = (const float*)d_in[0];
    const float* flow = (const float*)d_in[1];
    float* out = (float*)d_out;

    const int npix = BB * HH * WW;             // 1,048,576
    const int block = 256;
    const int grid = npix / block;             // 4096, divisible by 8
    warp_bilinear_kernel<<<grid, block, 0, stream>>>(src, flow, out);
}